// Round 1
// baseline (358.079 us; speedup 1.0000x reference)
//
#include <hip/hip_runtime.h>

#define CH    200
#define NE    8
#define OUTC  (CH - NE + 1)   // 193
#define HW    (128 * 128)     // 16384
#define VEC   4
#define THREADS 256
#define NCHUNKS 4

// Each thread: one float4 spatial position, slides 8-wide channel window.
// x read ~1.1x (chunk overlap), out written exactly once. Memory-bound.
__global__ __launch_bounds__(THREADS) void neigh_conv_kernel(
    const float* __restrict__ x, const float* __restrict__ W,
    const float* __restrict__ b, float* __restrict__ out) {
  __shared__ float sW[OUTC * NE];
  __shared__ float sb[OUTC];
  for (int i = threadIdx.x; i < OUTC * NE; i += THREADS) sW[i] = W[i];
  for (int i = threadIdx.x; i < OUTC; i += THREADS) sb[i] = b[i];
  __syncthreads();

  const int pos   = (blockIdx.x * THREADS + threadIdx.x) * VEC;  // elem offset in plane
  const int n     = blockIdx.y;
  const int chunk = blockIdx.z;
  const int c0 = (chunk * OUTC) / NCHUNKS;
  const int c1 = ((chunk + 1) * OUTC) / NCHUNKS;

  const float* xp = x + (size_t)n * CH * HW + pos;
  float* op       = out + (size_t)n * OUTC * HW + pos;

  // Preload window channels c0 .. c0+6, plus prefetch c0+7 into nxt.
  float4 win[NE - 1];
#pragma unroll
  for (int k = 0; k < NE - 1; ++k)
    win[k] = *(const float4*)(xp + (size_t)(c0 + k) * HW);
  float4 nxt = *(const float4*)(xp + (size_t)(c0 + NE - 1) * HW);

  for (int c = c0; c < c1; ++c) {
    const float4 cur = nxt;
    // Prefetch next iteration's channel (clamped in-bounds; last iter's
    // load is redundant but safe — 16 B/thread, negligible).
    const int cnext = min(c + NE, CH - 1);
    nxt = *(const float4*)(xp + (size_t)cnext * HW);

    const float bb = sb[c];
    float4 acc = make_float4(bb, bb, bb, bb);
#pragma unroll
    for (int k = 0; k < NE - 1; ++k) {
      const float w = sW[c * NE + k];
      acc.x += w * win[k].x;
      acc.y += w * win[k].y;
      acc.z += w * win[k].z;
      acc.w += w * win[k].w;
    }
    {
      const float w = sW[c * NE + NE - 1];
      acc.x += w * cur.x;
      acc.y += w * cur.y;
      acc.z += w * cur.z;
      acc.w += w * cur.w;
    }
    *(float4*)(op + (size_t)c * HW) = acc;

#pragma unroll
    for (int k = 0; k < NE - 2; ++k) win[k] = win[k + 1];
    win[NE - 2] = cur;
  }
}

extern "C" void kernel_launch(void* const* d_in, const int* in_sizes, int n_in,
                              void* d_out, int out_size, void* d_ws, size_t ws_size,
                              hipStream_t stream) {
  const float* x = (const float*)d_in[0];
  const float* W = (const float*)d_in[1];
  const float* b = (const float*)d_in[2];
  float* out = (float*)d_out;

  const int N = in_sizes[0] / (CH * HW);  // 16
  dim3 grid(HW / VEC / THREADS /*16*/, N, NCHUNKS);
  neigh_conv_kernel<<<grid, THREADS, 0, stream>>>(x, W, b, out);
}